// Round 1
// baseline (556.606 us; speedup 1.0000x reference)
//
#include <hip/hip_runtime.h>
#include <math.h>

// Problem constants
#define B 2
#define C 64
#define DD 64
#define HH 96
#define WW 96
#define HID 8
#define BC (B * C)                 // 128
#define SLICE (HH * WW)            // 9216 elements per d-slice
#define SLICE4 (SLICE / 4)         // 2304 float4 per d-slice
#define CHAN (DD * SLICE)          // 589824 elements per (b,c) channel
#define CHAN4 (CHAN / 4)           // 147456 float4 per channel
#define ROW4 (WW / 4)              // 24 float4 per row

// Workspace layout (floats):
//   [0, 128)          accum z-sums per (b,c)
//   [128, 128+64*27)  per-channel boundary-class effective weights
//   [1856, 1984)      gate per (b,c)
#define WS_ACC 0
#define WS_CLS 128
#define WS_GATE 1856

// ---------------------------------------------------------------------------
// Kernel 0: per-channel 27 boundary-class weight sums; also zero accumulators.
// class per axis: 0 = pos==0 (taps kd in {0,1}), 1 = interior (all),
//                 2 = pos==last (taps kd in {1,2})
__global__ void clsw_kernel(const float* __restrict__ dw_w, float* __restrict__ ws) {
    int c = blockIdx.x;   // 0..63
    int t = threadIdx.x;  // 0..63
    if (t < 27) {
        int cd = t / 9, r = t % 9, ch = r / 3, cw = r % 3;
        int kd0 = (cd == 2) ? 1 : 0, kd1 = (cd == 0) ? 1 : 2;
        int kh0 = (ch == 2) ? 1 : 0, kh1 = (ch == 0) ? 1 : 2;
        int kw0 = (cw == 2) ? 1 : 0, kw1 = (cw == 0) ? 1 : 2;
        float s = 0.f;
        for (int kd = kd0; kd <= kd1; ++kd)
            for (int kh = kh0; kh <= kh1; ++kh)
                for (int kw = kw0; kw <= kw1; ++kw)
                    s += dw_w[c * 27 + kd * 9 + kh * 3 + kw];
        ws[WS_CLS + c * 27 + t] = s;
    }
    if (t == 27) {
        ws[WS_ACC + c] = 0.f;
        ws[WS_ACC + C + c] = 0.f;
    }
}

// ---------------------------------------------------------------------------
// Kernel 1: weighted reduction of x -> accum[b,c].
// grid = (DD, BC); each block reduces one d-slice of one (b,c) channel.
__global__ __launch_bounds__(256) void reduce_kernel(const float* __restrict__ x,
                                                     float* __restrict__ ws) {
    const int bc = blockIdx.y;      // 0..127
    const int c = bc & (C - 1);
    const int d = blockIdx.x;       // 0..63
    const int cd = (d == 0) ? 0 : ((d == DD - 1) ? 2 : 1);

    __shared__ float w9[9];
    if (threadIdx.x < 9) w9[threadIdx.x] = ws[WS_CLS + c * 27 + cd * 9 + threadIdx.x];
    __syncthreads();

    const float4* x4 = (const float4*)x + (size_t)bc * CHAN4 + (size_t)d * SLICE4;
    float acc = 0.f;
    for (int t = threadIdx.x; t < SLICE4; t += 256) {
        float4 v = x4[t];
        int h = t / ROW4;
        int j = t - h * ROW4;
        int chc = (h == 0) ? 0 : ((h == HH - 1) ? 2 : 1);
        float wmid = w9[chc * 3 + 1];
        float w0 = (j == 0) ? w9[chc * 3 + 0] : wmid;
        float w3 = (j == ROW4 - 1) ? w9[chc * 3 + 2] : wmid;
        acc += v.x * w0 + (v.y + v.z) * wmid + v.w * w3;
    }
    // wave64 reduce
    for (int off = 32; off > 0; off >>= 1)
        acc += __shfl_down(acc, off, 64);
    __shared__ float part[4];
    int wave = threadIdx.x >> 6;
    if ((threadIdx.x & 63) == 0) part[wave] = acc;
    __syncthreads();
    if (threadIdx.x == 0) {
        float s = part[0] + part[1] + part[2] + part[3];
        atomicAdd(&ws[WS_ACC + bc], s);
    }
}

// ---------------------------------------------------------------------------
// Kernel 2: tiny SE MLP -> per-(b,c) sigmoid gate. 1 block, 128 threads.
__global__ void gate_kernel(const float* __restrict__ fc1_w, const float* __restrict__ fc1_b,
                            const float* __restrict__ fc2_w, const float* __restrict__ fc2_b,
                            float* __restrict__ ws) {
    __shared__ float zsh[BC];
    __shared__ float hsh[B * HID];
    int t = threadIdx.x;  // 0..127
    zsh[t] = ws[WS_ACC + t] * (1.0f / (float)CHAN);
    __syncthreads();
    if (t < B * HID) {
        int b = t >> 3, j = t & 7;
        float s = fc1_b[j];
        for (int cc = 0; cc < C; ++cc) s += fc1_w[j * C + cc] * zsh[b * C + cc];
        hsh[t] = (s >= 0.f) ? s : 0.01f * s;  // LeakyReLU(0.01)
    }
    __syncthreads();
    int b = t >> 6, cc = t & (C - 1);
    float s = fc2_b[cc];
    for (int j = 0; j < HID; ++j) s += fc2_w[cc * HID + j] * hsh[b * HID + j];
    ws[WS_GATE + t] = 1.f / (1.f + expf(-s));
}

// ---------------------------------------------------------------------------
// Kernel 3: out = x * gate[b,c]. grid = (CHAN4/256, BC), one float4/thread.
__global__ __launch_bounds__(256) void scale_kernel(const float* __restrict__ x,
                                                    const float* __restrict__ ws,
                                                    float* __restrict__ out) {
    const int bc = blockIdx.y;
    const float g = ws[WS_GATE + bc];
    size_t idx = (size_t)bc * CHAN4 + (size_t)blockIdx.x * 256 + threadIdx.x;
    float4 v = ((const float4*)x)[idx];
    float4 r;
    r.x = v.x * g; r.y = v.y * g; r.z = v.z * g; r.w = v.w * g;
    ((float4*)out)[idx] = r;
}

// ---------------------------------------------------------------------------
extern "C" void kernel_launch(void* const* d_in, const int* in_sizes, int n_in,
                              void* d_out, int out_size, void* d_ws, size_t ws_size,
                              hipStream_t stream) {
    const float* x     = (const float*)d_in[0];
    const float* dw_w  = (const float*)d_in[1];
    const float* fc1_w = (const float*)d_in[2];
    const float* fc1_b = (const float*)d_in[3];
    const float* fc2_w = (const float*)d_in[4];
    const float* fc2_b = (const float*)d_in[5];
    float* out = (float*)d_out;
    float* ws  = (float*)d_ws;

    clsw_kernel<<<dim3(C), dim3(64), 0, stream>>>(dw_w, ws);
    reduce_kernel<<<dim3(DD, BC), dim3(256), 0, stream>>>(x, ws);
    gate_kernel<<<dim3(1), dim3(BC), 0, stream>>>(fc1_w, fc1_b, fc2_w, fc2_b, ws);
    scale_kernel<<<dim3(CHAN4 / 256, BC), dim3(256), 0, stream>>>(x, ws, out);
}

// Round 2
// 546.204 us; speedup vs baseline: 1.0190x; 1.0190x over previous
//
#include <hip/hip_runtime.h>
#include <math.h>

// Problem constants
#define B 2
#define C 64
#define DD 64
#define HH 96
#define WW 96
#define HID 8
#define BC (B * C)                 // 128
#define SLICE (HH * WW)            // 9216 elements per d-slice
#define SLICE4 (SLICE / 4)         // 2304 float4 per d-slice
#define CHAN (DD * SLICE)          // 589824 elements per (b,c) channel
#define CHAN4 (CHAN / 4)           // 147456 float4 per channel
#define ROW4 (WW / 4)              // 24 float4 per row

#define RED_BX 16                  // reduce blocks along d per (b,c)
#define DPB (DD / RED_BX)          // 4 d-slices per reduce block
#define SC_F4 16                   // float4 per thread in scale kernel
#define SC_BX (CHAN4 / (256 * SC_F4))  // 36 scale blocks per (b,c)

// Workspace layout (floats):
#define WS_PART 0                  // [0, 2048): per-block reduce partials
#define WS_CLS  (BC * RED_BX)      // [2048, 2048+64*27): boundary-class weights
#define WS_GATE (WS_CLS + C * 27)  // [3776, 3904): per-(b,c) gate

typedef float f4 __attribute__((ext_vector_type(4)));

// ---------------------------------------------------------------------------
// Kernel 0: per-channel 27 boundary-class effective weight sums.
// class per axis: 0 = pos==0 (taps {0,1}), 1 = interior (all), 2 = pos==last ({1,2})
__global__ void clsw_kernel(const float* __restrict__ dw_w, float* __restrict__ ws) {
    int c = blockIdx.x;   // 0..63
    int t = threadIdx.x;  // 0..63
    if (t < 27) {
        int cd = t / 9, r = t % 9, ch = r / 3, cw = r % 3;
        int kd0 = (cd == 2) ? 1 : 0, kd1 = (cd == 0) ? 1 : 2;
        int kh0 = (ch == 2) ? 1 : 0, kh1 = (ch == 0) ? 1 : 2;
        int kw0 = (cw == 2) ? 1 : 0, kw1 = (cw == 0) ? 1 : 2;
        float s = 0.f;
        for (int kd = kd0; kd <= kd1; ++kd)
            for (int kh = kh0; kh <= kh1; ++kh)
                for (int kw = kw0; kw <= kw1; ++kw)
                    s += dw_w[c * 27 + kd * 9 + kh * 3 + kw];
        ws[WS_CLS + c * 27 + t] = s;
    }
}

// ---------------------------------------------------------------------------
// Kernel 1: weighted reduction of x -> per-block partials (atomic-free).
// grid = (RED_BX, BC); each block reduces DPB d-slices of one (b,c) channel.
__global__ __launch_bounds__(256) void reduce_kernel(const float* __restrict__ x,
                                                     float* __restrict__ ws) {
    const int bc = blockIdx.y;
    const int c  = bc & (C - 1);
    const int d0 = blockIdx.x * DPB;
    const int tid = threadIdx.x;

    __shared__ float w9[9];
    __shared__ float part[4];

    const f4* xb = (const f4*)x + (size_t)bc * CHAN4;
    float acc = 0.f;

    const int h0 = tid / ROW4;           // one div per thread, outside the loop
    const int j0 = tid - h0 * ROW4;

    for (int sd = 0; sd < DPB; ++sd) {
        const int d  = d0 + sd;
        const int cd = (d == 0) ? 0 : ((d == DD - 1) ? 2 : 1);
        __syncthreads();   // guard w9 reuse across slices
        if (tid < 9) w9[tid] = ws[WS_CLS + c * 27 + cd * 9 + tid];
        __syncthreads();

        const f4* x4 = xb + (size_t)d * SLICE4;
        int h = h0, j = j0;
        #pragma unroll
        for (int it = 0; it < SLICE4 / 256; ++it) {   // 9 iterations
            f4 v = x4[it * 256 + tid];
            int chc = (h == 0) ? 0 : ((h == HH - 1) ? 2 : 1);
            float wmid = w9[chc * 3 + 1];
            float w0 = (j == 0) ? w9[chc * 3 + 0] : wmid;
            float w3 = (j == ROW4 - 1) ? w9[chc * 3 + 2] : wmid;
            acc += v.x * w0 + (v.y + v.z) * wmid + v.w * w3;
            // advance linear index by 256 = 10*24 + 16
            h += 10; j += 16;
            if (j >= ROW4) { j -= ROW4; h += 1; }
        }
    }

    for (int off = 32; off > 0; off >>= 1)
        acc += __shfl_down(acc, off, 64);
    if ((tid & 63) == 0) part[tid >> 6] = acc;
    __syncthreads();
    if (tid == 0)
        ws[WS_PART + bc * RED_BX + blockIdx.x] = part[0] + part[1] + part[2] + part[3];
}

// ---------------------------------------------------------------------------
// Kernel 2: sum partials -> z -> SE MLP -> sigmoid gate. 1 block, 128 threads.
__global__ void gate_kernel(const float* __restrict__ fc1_w, const float* __restrict__ fc1_b,
                            const float* __restrict__ fc2_w, const float* __restrict__ fc2_b,
                            float* __restrict__ ws) {
    __shared__ float zsh[BC];
    __shared__ float hsh[B * HID];
    int t = threadIdx.x;  // 0..127
    float s0 = 0.f;
    for (int p = 0; p < RED_BX; ++p) s0 += ws[WS_PART + t * RED_BX + p];
    zsh[t] = s0 * (1.0f / (float)CHAN);
    __syncthreads();
    if (t < B * HID) {
        int b = t >> 3, j = t & 7;
        float s = fc1_b[j];
        for (int cc = 0; cc < C; ++cc) s += fc1_w[j * C + cc] * zsh[b * C + cc];
        hsh[t] = (s >= 0.f) ? s : 0.01f * s;  // LeakyReLU(0.01)
    }
    __syncthreads();
    int b = t >> 6, cc = t & (C - 1);
    float s = fc2_b[cc];
    for (int j = 0; j < HID; ++j) s += fc2_w[cc * HID + j] * hsh[b * HID + j];
    ws[WS_GATE + t] = 1.f / (1.f + expf(-s));
}

// ---------------------------------------------------------------------------
// Kernel 3: out = x * gate[b,c]. grid = (SC_BX, BC), SC_F4 float4 per thread,
// non-temporal (out never re-read; don't evict x from L3 during this pass).
__global__ __launch_bounds__(256) void scale_kernel(const float* __restrict__ x,
                                                    const float* __restrict__ ws,
                                                    float* __restrict__ out) {
    const int bc = blockIdx.y;
    const float g = ws[WS_GATE + bc];
    const size_t base = (size_t)bc * CHAN4 + (size_t)blockIdx.x * (256 * SC_F4) + threadIdx.x;
    const f4* xp = (const f4*)x;
    f4* op = (f4*)out;
    #pragma unroll
    for (int k = 0; k < SC_F4; ++k) {
        size_t idx = base + (size_t)k * 256;
        f4 v = __builtin_nontemporal_load(&xp[idx]);
        f4 r = v * g;
        __builtin_nontemporal_store(r, &op[idx]);
    }
}

// ---------------------------------------------------------------------------
extern "C" void kernel_launch(void* const* d_in, const int* in_sizes, int n_in,
                              void* d_out, int out_size, void* d_ws, size_t ws_size,
                              hipStream_t stream) {
    const float* x     = (const float*)d_in[0];
    const float* dw_w  = (const float*)d_in[1];
    const float* fc1_w = (const float*)d_in[2];
    const float* fc1_b = (const float*)d_in[3];
    const float* fc2_w = (const float*)d_in[4];
    const float* fc2_b = (const float*)d_in[5];
    float* out = (float*)d_out;
    float* ws  = (float*)d_ws;

    clsw_kernel<<<dim3(C), dim3(64), 0, stream>>>(dw_w, ws);
    reduce_kernel<<<dim3(RED_BX, BC), dim3(256), 0, stream>>>(x, ws);
    gate_kernel<<<dim3(1), dim3(BC), 0, stream>>>(fc1_w, fc1_b, fc2_w, fc2_b, ws);
    scale_kernel<<<dim3(SC_BX, BC), dim3(256), 0, stream>>>(x, ws, out);
}